// Round 1
// baseline (3388.555 us; speedup 1.0000x reference)
//
#include <hip/hip_runtime.h>

// out[b,p,c] = sum_s (x[b,s,c]-x[b,S-1,c]) * W[c,p,s] + bias[c,p] + x[b,S-1,c]
// B=128, S=672, P=168, C=500. All fp32.

namespace {
constexpr int Bn = 128, Sn = 672, Pn = 168, Cn = 500;
constexpr int CB = 16;        // c per block
constexpr int BBt = 32;       // b per block
constexpr int PBt = 28;       // p per block (168 = 6*28 exact)
constexpr int SB = 8;         // s chunk
constexpr int STRIDE = SB + 2; // 10 floats: even (float2-aligned), decent bank spread
constexpr int NCH = Sn / SB;  // 84
constexpr int BT = 8, PT = 7; // per-thread register tile (8 b x 7 p, one c)
constexpr int PBLK = Pn / PBt; // 6
constexpr int BBLK = Bn / BBt; // 4
constexpr int CBLK = (Cn + CB - 1) / CB; // 32 (last block has 4 valid c)
}

__global__ __launch_bounds__(256, 4)
void tsmix_kernel(const float* __restrict__ x, const float* __restrict__ W,
                  const float* __restrict__ bias, float* __restrict__ out) {
  __shared__ float xs[BBt * CB * STRIDE]; // [(bb*CB+cc)*STRIDE + ss]  20.0 KB
  __shared__ float ws[PBt * CB * STRIDE]; // [(pp*CB+cc)*STRIDE + ss]  17.5 KB

  const int tid = threadIdx.x;
  const int c0 = blockIdx.y * CB;
  const int b0 = (blockIdx.x / PBLK) * BBt;
  const int p0 = (blockIdx.x % PBLK) * PBt;

  // ---------- chunk-invariant staging descriptors ----------
  // x tile: 32b x 8s x 16c = 4096 floats = 1024 float4 (4 per thread), lanes along c
  int xg[4];      // global element offset for s0=0
  int xw[4];      // LDS write base
  float4 xlv[4];  // x[b, S-1, c..c+3] (chunk-invariant)
  #pragma unroll
  for (int k = 0; k < 4; ++k) {
    const int idx = k * 256 + tid;
    const int cq = (idx & 3) * 4;    // c offset within tile (float4 granularity)
    const int ss = (idx >> 2) & 7;
    const int bb = idx >> 5;
    int c = c0 + cq;
    if (c + 3 >= Cn) c = Cn - 4;     // clamp (stays 16B aligned; Cn-4=496 ≡ 0 mod 4)
    xg[k] = ((b0 + bb) * Sn + ss) * Cn + c;
    xw[k] = (bb * CB + cq) * STRIDE + ss;
    xlv[k] = *(const float4*)&x[((b0 + bb) * Sn + (Sn - 1)) * Cn + c];
  }
  // W tile: 16c x 28p x 8s = 3584 floats = 896 float4, lanes along s
  int wg[4], ww[4];
  bool wok[4];
  #pragma unroll
  for (int k = 0; k < 4; ++k) {
    const int idx = k * 256 + tid;
    wok[k] = (idx < CB * PBt * 2);   // 896
    const int ss = (idx & 1) * 4;
    const int r = idx >> 1;
    const int pp = r % PBt;
    const int cc = r / PBt;
    int c = c0 + cc;
    if (c >= Cn) c = Cn - 1;
    wg[k] = (c * Pn + (p0 + pp)) * Sn + ss;
    ww[k] = (pp * CB + cc) * STRIDE + ss;
  }

  // ---------- compute-thread coordinates ----------
  const int c_idx = tid & 15;
  const int b_idx = (tid >> 4) & 3;
  const int p_idx = tid >> 6;
  const int xb = (b_idx * BT * CB + c_idx) * STRIDE;
  const int wb = (p_idx * PT * CB + c_idx) * STRIDE;

  float acc[BT][PT];
  #pragma unroll
  for (int i = 0; i < BT; ++i)
    #pragma unroll
    for (int j = 0; j < PT; ++j) acc[i][j] = 0.0f;

  int xoff = 0, woff = 0;
  for (int ch = 0; ch < NCH; ++ch) {
    // issue global loads (regs only; overlaps prev compute tail)
    float4 xv[4], wv[4];
    #pragma unroll
    for (int k = 0; k < 4; ++k) {
      const float4 t = *(const float4*)&x[xg[k] + xoff];
      xv[k] = make_float4(t.x - xlv[k].x, t.y - xlv[k].y,
                          t.z - xlv[k].z, t.w - xlv[k].w);
    }
    #pragma unroll
    for (int k = 0; k < 4; ++k)
      if (wok[k]) wv[k] = *(const float4*)&W[wg[k] + woff];

    __syncthreads(); // previous chunk's compute done -> LDS reusable

    #pragma unroll
    for (int k = 0; k < 4; ++k) { // x: 4 scalar writes, stride 10 (transpose c->row)
      xs[xw[k]]              = xv[k].x;
      xs[xw[k] + STRIDE]     = xv[k].y;
      xs[xw[k] + 2 * STRIDE] = xv[k].z;
      xs[xw[k] + 3 * STRIDE] = xv[k].w;
    }
    #pragma unroll
    for (int k = 0; k < 4; ++k)
      if (wok[k]) { // W: contiguous along s in LDS
        *(float2*)&ws[ww[k]]     = make_float2(wv[k].x, wv[k].y);
        *(float2*)&ws[ww[k] + 2] = make_float2(wv[k].z, wv[k].w);
      }

    __syncthreads(); // tile ready

    #pragma unroll
    for (int sp = 0; sp < SB; sp += 2) {
      float2 xf[BT], wf[PT];
      #pragma unroll
      for (int i = 0; i < BT; ++i)
        xf[i] = *(const float2*)&xs[xb + i * CB * STRIDE + sp];
      #pragma unroll
      for (int j = 0; j < PT; ++j)
        wf[j] = *(const float2*)&ws[wb + j * CB * STRIDE + sp];
      #pragma unroll
      for (int i = 0; i < BT; ++i)
        #pragma unroll
        for (int j = 0; j < PT; ++j) {
          acc[i][j] += xf[i].x * wf[j].x;
          acc[i][j] += xf[i].y * wf[j].y;
        }
    }

    xoff += SB * Cn; // 4000
    woff += SB;      // 8
  }

  // ---------- epilogue: + bias + seq_last, store ----------
  const int c = c0 + c_idx;
  if (c < Cn) {
    const int bb0 = b0 + b_idx * BT;
    const int pp0 = p0 + p_idx * PT;
    float xl[BT], bi[PT];
    #pragma unroll
    for (int i = 0; i < BT; ++i)
      xl[i] = x[((bb0 + i) * Sn + (Sn - 1)) * Cn + c];
    #pragma unroll
    for (int j = 0; j < PT; ++j)
      bi[j] = bias[c * Pn + pp0 + j];
    #pragma unroll
    for (int i = 0; i < BT; ++i)
      #pragma unroll
      for (int j = 0; j < PT; ++j)
        out[((bb0 + i) * Pn + (pp0 + j)) * Cn + c] = acc[i][j] + bi[j] + xl[i];
  }
}

extern "C" void kernel_launch(void* const* d_in, const int* in_sizes, int n_in,
                              void* d_out, int out_size, void* d_ws, size_t ws_size,
                              hipStream_t stream) {
  (void)in_sizes; (void)n_in; (void)d_ws; (void)ws_size; (void)out_size;
  const float* x  = (const float*)d_in[0];
  const float* W  = (const float*)d_in[1];
  const float* bv = (const float*)d_in[2];
  float* out = (float*)d_out;

  dim3 grid(BBLK * PBLK, CBLK); // x: 24 (b,p) tiles fast; y: 32 c-ranges slow (L2 locality)
  dim3 block(256);
  hipLaunchKernelGGL(tsmix_kernel, grid, block, 0, stream, x, W, bv, out);
}

// Round 2
// 754.907 us; speedup vs baseline: 4.4887x; 4.4887x over previous
//
#include <hip/hip_runtime.h>

// out[b,p,c] = sum_s (x[b,s,c]-x[b,S-1,c]) * W[c,p,s] + bias[c,p] + x[b,S-1,c]
//            = sum_s x*W  +  bias  +  xlast*(1 - sum_s W)
// B=128, S=672, P=168, C=500. All fp32.

namespace {
constexpr int Bn = 128, Sn = 672, Pn = 168, Cn = 500;
constexpr int CB = 16;        // c per block
constexpr int BBt = 32;       // b per block
constexpr int PBt = 28;       // p per block (168 = 6*28 exact)
constexpr int SB = 8;         // s chunk
constexpr int STRIDE = SB + 2; // 10 floats
constexpr int NCH = Sn / SB;  // 84
constexpr int BT = 8, PT = 7; // per-thread register tile (8 b x 7 p, one c)
constexpr int PBLK = Pn / PBt; // 6
constexpr int BBLK = Bn / BBt; // 4
constexpr int CBLK = (Cn + CB - 1) / CB; // 32
}

__global__ __launch_bounds__(256, 2)  // cap 256 VGPR: the 56-acc tile + staging needs ~160
void tsmix_kernel(const float* __restrict__ x, const float* __restrict__ W,
                  const float* __restrict__ bias, float* __restrict__ out) {
  __shared__ float xs[BBt * CB * STRIDE]; // [(bb*CB+cc)*STRIDE + ss]  20.0 KB
  __shared__ float ws[PBt * CB * STRIDE]; // [(pp*CB+cc)*STRIDE + ss]  17.5 KB

  const int tid = threadIdx.x;
  const int c0 = blockIdx.y * CB;
  const int b0 = (blockIdx.x / PBLK) * BBt;
  const int p0 = (blockIdx.x % PBLK) * PBt;

  // ---------- staging descriptors (chunk-invariant) ----------
  // x tile: 32b x 8s x 16c = 1024 float4 (4/thread), lanes along c
  int xg[4], xw[4];
  #pragma unroll
  for (int k = 0; k < 4; ++k) {
    const int idx = k * 256 + tid;
    const int cq = (idx & 3) * 4;
    const int ss = (idx >> 2) & 7;
    const int bb = idx >> 5;
    int c = c0 + cq;
    if (c + 3 >= Cn) c = Cn - 4;     // clamp, stays 16B-aligned (496%4==0)
    xg[k] = ((b0 + bb) * Sn + ss) * Cn + c;
    xw[k] = (bb * CB + cq) * STRIDE + ss;
  }
  // W tile: 16c x 28p x 8s = 896 float4, lanes along s
  int wg[4], ww[4];
  bool wok[4];
  #pragma unroll
  for (int k = 0; k < 4; ++k) {
    const int idx = k * 256 + tid;
    wok[k] = (idx < CB * PBt * 2);   // 896
    const int ss = (idx & 1) * 4;
    const int r = idx >> 1;
    const int pp = r % PBt;
    const int cc = r / PBt;
    int c = c0 + cc;
    if (c >= Cn) c = Cn - 1;
    wg[k] = (c * Pn + (p0 + pp)) * Sn + ss;
    ww[k] = (pp * CB + cc) * STRIDE + ss;
  }

  // ---------- compute-thread coordinates ----------
  const int c_idx = tid & 15;
  const int b_idx = (tid >> 4) & 3;
  const int p_idx = tid >> 6;
  const int xb = (b_idx * BT * CB + c_idx) * STRIDE;
  const int wb = (p_idx * PT * CB + c_idx) * STRIDE;

  float acc[BT][PT];
  #pragma unroll
  for (int i = 0; i < BT; ++i)
    #pragma unroll
    for (int j = 0; j < PT; ++j) acc[i][j] = 0.0f;
  float swsum[PT];
  #pragma unroll
  for (int j = 0; j < PT; ++j) swsum[j] = 0.0f;

  // ---------- prologue: load chunk 0 ----------
  float4 xv[4], wv[4];
  #pragma unroll
  for (int k = 0; k < 4; ++k) xv[k] = *(const float4*)&x[xg[k]];
  #pragma unroll
  for (int k = 0; k < 4; ++k)
    if (wok[k]) wv[k] = *(const float4*)&W[wg[k]];

  int xoff = SB * Cn, woff = SB; // offsets of the NEXT chunk

  for (int ch = 0; ch < NCH; ++ch) {
    __syncthreads(); // previous chunk's compute done -> LDS reusable

    #pragma unroll
    for (int k = 0; k < 4; ++k) { // x: transpose c->rows, s contiguous
      xs[xw[k]]              = xv[k].x;
      xs[xw[k] + STRIDE]     = xv[k].y;
      xs[xw[k] + 2 * STRIDE] = xv[k].z;
      xs[xw[k] + 3 * STRIDE] = xv[k].w;
    }
    #pragma unroll
    for (int k = 0; k < 4; ++k)
      if (wok[k]) {
        *(float2*)&ws[ww[k]]     = make_float2(wv[k].x, wv[k].y);
        *(float2*)&ws[ww[k] + 2] = make_float2(wv[k].z, wv[k].w);
      }

    __syncthreads(); // tile ready

    // issue next chunk's global loads NOW; latency hides under the FMA block
    if (ch + 1 < NCH) {
      #pragma unroll
      for (int k = 0; k < 4; ++k) xv[k] = *(const float4*)&x[xg[k] + xoff];
      #pragma unroll
      for (int k = 0; k < 4; ++k)
        if (wok[k]) wv[k] = *(const float4*)&W[wg[k] + woff];
      xoff += SB * Cn;
      woff += SB;
    }

    #pragma unroll
    for (int sp = 0; sp < SB; sp += 2) {
      float2 xf[BT], wf[PT];
      #pragma unroll
      for (int i = 0; i < BT; ++i)
        xf[i] = *(const float2*)&xs[xb + i * CB * STRIDE + sp];
      #pragma unroll
      for (int j = 0; j < PT; ++j)
        wf[j] = *(const float2*)&ws[wb + j * CB * STRIDE + sp];
      #pragma unroll
      for (int j = 0; j < PT; ++j)
        swsum[j] += wf[j].x + wf[j].y;   // running sum_s W for the xlast fold
      #pragma unroll
      for (int i = 0; i < BT; ++i)
        #pragma unroll
        for (int j = 0; j < PT; ++j) {
          acc[i][j] += xf[i].x * wf[j].x;
          acc[i][j] += xf[i].y * wf[j].y;
        }
    }
  }

  // ---------- epilogue: out = acc + bias + xlast*(1 - swsum) ----------
  const int c = c0 + c_idx;
  if (c < Cn) {
    const int bb0 = b0 + b_idx * BT;
    const int pp0 = p0 + p_idx * PT;
    float xl[BT], bi[PT];
    #pragma unroll
    for (int i = 0; i < BT; ++i)
      xl[i] = x[((bb0 + i) * Sn + (Sn - 1)) * Cn + c];
    #pragma unroll
    for (int j = 0; j < PT; ++j)
      bi[j] = bias[c * Pn + pp0 + j];
    #pragma unroll
    for (int i = 0; i < BT; ++i)
      #pragma unroll
      for (int j = 0; j < PT; ++j)
        out[((bb0 + i) * Pn + (pp0 + j)) * Cn + c] =
            acc[i][j] + bi[j] + xl[i] * (1.0f - swsum[j]);
  }
}

extern "C" void kernel_launch(void* const* d_in, const int* in_sizes, int n_in,
                              void* d_out, int out_size, void* d_ws, size_t ws_size,
                              hipStream_t stream) {
  (void)in_sizes; (void)n_in; (void)d_ws; (void)ws_size; (void)out_size;
  const float* x  = (const float*)d_in[0];
  const float* W  = (const float*)d_in[1];
  const float* bv = (const float*)d_in[2];
  float* out = (float*)d_out;

  dim3 grid(BBLK * PBLK, CBLK); // 24 (b,p) tiles fast, 32 c-ranges slow (LLC locality)
  dim3 block(256);
  hipLaunchKernelGGL(tsmix_kernel, grid, block, 0, stream, x, W, bv, out);
}

// Round 3
// 491.281 us; speedup vs baseline: 6.8974x; 1.5366x over previous
//
#include <hip/hip_runtime.h>

// out[b,p,c] = sum_s (x[b,s,c]-x[b,S-1,c]) * W[c,p,s] + bias[c,p] + x[b,S-1,c]
// Two-kernel plan:
//   1) xpose: x'(c,b,s) = bf16(x[b,s,c] - x[b,S-1,c])  into d_ws (86 MB)
//   2) gemm : 500 batched 128x168x672 GEMMs via mfma_f32_16x16x32_bf16,
//             LDS-free, both operands direct-from-global (L2/LLC-cached reuse).

typedef __attribute__((ext_vector_type(8))) short short8;   // 8 bf16 in 4 VGPRs
typedef __attribute__((ext_vector_type(4))) float floatx4;  // MFMA C/D

namespace {
constexpr int Bn = 128, Sn = 672, Pn = 168, Cn = 500;
constexpr int XQ_CSTRIDE = Bn * Sn;   // 86016 bf16 elems per c-plane of x'
constexpr int TC = 64, TS = 96;       // xpose tile: 64 c x 96 s (per b)
constexpr int TROW = TS + 12;         // 108: stride%4==0 (b64-aligned rows), 8-way not 16-way banks
}

__device__ __forceinline__ unsigned short f2bf(float f) {  // RTNE f32->bf16
  unsigned int u = __builtin_bit_cast(unsigned int, f);
  u += 0x7fffu + ((u >> 16) & 1u);
  return (unsigned short)(u >> 16);
}

// ---------------------------------------------------------------- xpose ----
// grid (128 b, 7 sT, 8 cT), block 256. read lanes along c, write rows along s.
__global__ __launch_bounds__(256)
void xpose_kernel(const float* __restrict__ x, unsigned short* __restrict__ xq) {
  __shared__ unsigned short T[TC][TROW];
  const int b  = blockIdx.x;
  const int s0 = blockIdx.y * TS;
  const int c0 = blockIdx.z * TC;
  const int t  = threadIdx.x;

  #pragma unroll
  for (int i = 0; i < 6; ++i) {
    const int idx = t + i * 256;       // 0..1535 = 96 s-rows x 16 c-quads
    const int sr  = idx >> 4;          // 0..95
    const int cq  = (idx & 15) * 4;    // 0..60
    int c = c0 + cq;
    if (c > Cn - 4) c = Cn - 4;        // clamp to 496 (16B-aligned); dup writes identical
    const int rel = c - c0;
    const float4 xv = *(const float4*)&x[(size_t)(b * Sn + s0 + sr) * Cn + c];
    const float4 xl = *(const float4*)&x[(size_t)(b * Sn + (Sn - 1)) * Cn + c];
    T[rel + 0][sr] = f2bf(xv.x - xl.x);
    T[rel + 1][sr] = f2bf(xv.y - xl.y);
    T[rel + 2][sr] = f2bf(xv.z - xl.z);
    T[rel + 3][sr] = f2bf(xv.w - xl.w);
  }
  __syncthreads();
  #pragma unroll
  for (int i = 0; i < 6; ++i) {
    const int idx = t + i * 256;       // 64 c-rows x 24 s-quads
    const int cr  = idx / 24;
    const int sq  = (idx % 24) * 4;
    const int c   = c0 + cr;
    if (c >= Cn) continue;             // skip pad rows (never read)
    const ushort4 v = *(const ushort4*)&T[cr][sq];
    *(ushort4*)&xq[(size_t)c * XQ_CSTRIDE + b * Sn + s0 + sq] = v;
  }
}

// ----------------------------------------------------------------- gemm ----
// block = 256 thr = 4 waves; tile 64b x 16p x 16c; wave = one 16b sub-tile.
// grid.x = pt*2+bh (22; b-pair adjacent -> concurrent W reuse), grid.y = cr (32).
// No LDS, no barriers: A from x' (16B/lane contiguous), B from W fp32 (cvt in regs).
__global__ __launch_bounds__(256)
void gemm_kernel(const unsigned short* __restrict__ xq, const float* __restrict__ W,
                 const float* __restrict__ bias, const float* __restrict__ x,
                 float* __restrict__ out) {
  const int bh = blockIdx.x & 1;
  const int pt = blockIdx.x >> 1;
  const int cr = blockIdx.y;
  const int c0 = (cr == 31) ? (Cn - 16) : cr * 16;  // last range overlaps: identical dup stores
  const int lane = threadIdx.x & 63;
  const int wave = threadIdx.x >> 6;
  const int r16  = lane & 15;          // A-row (b) / B-col (p) index
  const int kg   = lane >> 4;          // k-octet: k = kg*8 + elem

  const int b_base = bh * 64 + wave * 16;
  const int p0 = pt * 16;
  const int p  = p0 + r16;
  const int pcl = (p < Pn) ? p : (Pn - 1);   // clamp loads; stores masked below

  const unsigned short* Ap = xq + (size_t)c0 * XQ_CSTRIDE + (size_t)(b_base + r16) * Sn + kg * 8;
  const float*          Bp = W  + ((size_t)c0 * Pn + pcl) * Sn + kg * 8;

  floatx4 acc[16];
  #pragma unroll
  for (int cc = 0; cc < 16; ++cc) acc[cc] = (floatx4){0.f, 0.f, 0.f, 0.f};

  for (int sch = 0; sch < Sn / 32; ++sch) {
    const int soff = sch * 32;
    #pragma unroll
    for (int cc = 0; cc < 16; ++cc) {
      const short8 a  = *(const short8*)(Ap + (size_t)cc * XQ_CSTRIDE + soff);
      const float4 w0 = *(const float4*)(Bp + (size_t)cc * (Pn * Sn) + soff);
      const float4 w1 = *(const float4*)(Bp + (size_t)cc * (Pn * Sn) + soff + 4);
      short8 wb;
      wb[0] = (short)f2bf(w0.x); wb[1] = (short)f2bf(w0.y);
      wb[2] = (short)f2bf(w0.z); wb[3] = (short)f2bf(w0.w);
      wb[4] = (short)f2bf(w1.x); wb[5] = (short)f2bf(w1.y);
      wb[6] = (short)f2bf(w1.z); wb[7] = (short)f2bf(w1.w);
      acc[cc] = __builtin_amdgcn_mfma_f32_16x16x32_bf16(a, wb, acc[cc], 0, 0, 0);
    }
  }

  if (p >= Pn) return;  // masked p-columns of the 11th tile
  // D layout: col = lane&15 (=p), row = kg*4 + reg (=b offset)
  #pragma unroll
  for (int r = 0; r < 4; ++r) {
    const int bo = b_base + kg * 4 + r;
    float4 xl[4];
    #pragma unroll
    for (int q = 0; q < 4; ++q)
      xl[q] = *(const float4*)&x[(size_t)(bo * Sn + Sn - 1) * Cn + c0 + q * 4];
    float vals[16];
    #pragma unroll
    for (int cc = 0; cc < 16; ++cc)
      vals[cc] = acc[cc][r] + bias[(size_t)(c0 + cc) * Pn + p];
    #pragma unroll
    for (int q = 0; q < 4; ++q) {
      float4 st;
      st.x = vals[q * 4 + 0] + xl[q].x;
      st.y = vals[q * 4 + 1] + xl[q].y;
      st.z = vals[q * 4 + 2] + xl[q].z;
      st.w = vals[q * 4 + 3] + xl[q].w;
      *(float4*)&out[(size_t)(bo * Pn + p) * Cn + c0 + q * 4] = st;  // 64B/lane full-line
    }
  }
}

extern "C" void kernel_launch(void* const* d_in, const int* in_sizes, int n_in,
                              void* d_out, int out_size, void* d_ws, size_t ws_size,
                              hipStream_t stream) {
  (void)in_sizes; (void)n_in; (void)out_size; (void)ws_size;  // needs ws >= 86,016,000 B
  const float* x  = (const float*)d_in[0];
  const float* W  = (const float*)d_in[1];
  const float* bv = (const float*)d_in[2];
  float* out = (float*)d_out;
  unsigned short* xq = (unsigned short*)d_ws;

  hipLaunchKernelGGL(xpose_kernel, dim3(Bn, Sn / TS, (Cn + TC - 1) / TC), dim3(256), 0, stream,
                     x, xq);
  hipLaunchKernelGGL(gemm_kernel, dim3(22, 32), dim3(256), 0, stream,
                     xq, W, bv, x, out);
}

// Round 4
// 368.183 us; speedup vs baseline: 9.2034x; 1.3343x over previous
//
#include <hip/hip_runtime.h>

// out[b,p,c] = sum_s (x[b,s,c]-x[b,S-1,c]) * W[c,p,s] + bias[c,p] + x[b,S-1,c]
// Two-kernel plan:
//   1) xpose: x'(c,b,s) = bf16(x[b,s,c] - x[b,S-1,c]) into d_ws (86 MB) — at BW floor.
//   2) gemm : mfma_f32_16x16x32_bf16, LDS-free, direct-from-global.
//      Round-4 change: per-wave tile 16b x 16p x 4c (was 16c) -> 4x the waves
//      (11000 waves, ~43/CU launched) to convert latency-bound -> BW-bound.

typedef __attribute__((ext_vector_type(8))) short short8;   // 8 bf16 in 4 VGPRs
typedef __attribute__((ext_vector_type(4))) float floatx4;  // MFMA C/D

namespace {
constexpr int Bn = 128, Sn = 672, Pn = 168, Cn = 500;
constexpr int XQ_CSTRIDE = Bn * Sn;   // 86016 bf16 per c-plane of x'
constexpr int TC = 64, TS = 96;       // xpose tile
constexpr int TROW = TS + 12;
constexpr int CB = 4;                 // c-planes per wave (500 = 4*125 exact)
constexpr int NSCH = Sn / 32;         // 21
}

__device__ __forceinline__ unsigned short f2bf(float f) {  // RTNE f32->bf16
  unsigned int u = __builtin_bit_cast(unsigned int, f);
  u += 0x7fffu + ((u >> 16) & 1u);
  return (unsigned short)(u >> 16);
}

// ---------------------------------------------------------------- xpose ----
__global__ __launch_bounds__(256)
void xpose_kernel(const float* __restrict__ x, unsigned short* __restrict__ xq) {
  __shared__ unsigned short T[TC][TROW];
  const int b  = blockIdx.x;
  const int s0 = blockIdx.y * TS;
  const int c0 = blockIdx.z * TC;
  const int t  = threadIdx.x;

  #pragma unroll
  for (int i = 0; i < 6; ++i) {
    const int idx = t + i * 256;       // 96 s-rows x 16 c-quads
    const int sr  = idx >> 4;
    const int cq  = (idx & 15) * 4;
    int c = c0 + cq;
    if (c > Cn - 4) c = Cn - 4;        // clamp (16B-aligned); dup writes identical
    const int rel = c - c0;
    const float4 xv = *(const float4*)&x[(size_t)(b * Sn + s0 + sr) * Cn + c];
    const float4 xl = *(const float4*)&x[(size_t)(b * Sn + (Sn - 1)) * Cn + c];
    T[rel + 0][sr] = f2bf(xv.x - xl.x);
    T[rel + 1][sr] = f2bf(xv.y - xl.y);
    T[rel + 2][sr] = f2bf(xv.z - xl.z);
    T[rel + 3][sr] = f2bf(xv.w - xl.w);
  }
  __syncthreads();
  #pragma unroll
  for (int i = 0; i < 6; ++i) {
    const int idx = t + i * 256;       // 64 c-rows x 24 s-quads
    const int cr  = idx / 24;
    const int sq  = (idx % 24) * 4;
    const int c   = c0 + cr;
    if (c >= Cn) continue;
    const ushort4 v = *(const ushort4*)&T[cr][sq];
    *(ushort4*)&xq[(size_t)c * XQ_CSTRIDE + b * Sn + s0 + sq] = v;
  }
}

// ----------------------------------------------------------------- gemm ----
// block = 4 waves; wave = 16b x 16p x 4c. grid (22 = bh fast + pt, 125 = cr).
// All 4 waves of a block read identical W (L1); bh-pairs share W via L2/LLC;
// x' (86 MB) re-reads across pt are LLC-served.
__global__ __launch_bounds__(256)
void gemm_kernel(const unsigned short* __restrict__ xq, const float* __restrict__ W,
                 const float* __restrict__ bias, const float* __restrict__ x,
                 float* __restrict__ out) {
  const int bh = blockIdx.x & 1;
  const int pt = blockIdx.x >> 1;
  const int c0 = blockIdx.y * CB;      // 0..496, exact
  const int lane = threadIdx.x & 63;
  const int wave = threadIdx.x >> 6;
  const int r16  = lane & 15;          // A-row (b) / B-col (p)
  const int kg   = lane >> 4;          // k-octet

  const int b_base = bh * 64 + wave * 16;
  const int p  = pt * 16 + r16;
  const int pcl = (p < Pn) ? p : (Pn - 1);   // clamp loads; stores masked

  const unsigned short* Ap = xq + (size_t)c0 * XQ_CSTRIDE + (size_t)(b_base + r16) * Sn + kg * 8;
  const float*          Bp = W  + ((size_t)c0 * Pn + pcl) * Sn + kg * 8;

  floatx4 acc[CB];
  #pragma unroll
  for (int cc = 0; cc < CB; ++cc) acc[cc] = (floatx4){0.f, 0.f, 0.f, 0.f};

  // prefetch chunk 0
  short8 aN[CB]; float4 w0N[CB], w1N[CB];
  #pragma unroll
  for (int cc = 0; cc < CB; ++cc) {
    aN[cc]  = *(const short8*)(Ap + (size_t)cc * XQ_CSTRIDE);
    w0N[cc] = *(const float4*)(Bp + (size_t)cc * (Pn * Sn));
    w1N[cc] = *(const float4*)(Bp + (size_t)cc * (Pn * Sn) + 4);
  }

  for (int sch = 0; sch < NSCH; ++sch) {
    short8 a[CB]; float4 u0[CB], u1[CB];
    #pragma unroll
    for (int cc = 0; cc < CB; ++cc) { a[cc] = aN[cc]; u0[cc] = w0N[cc]; u1[cc] = w1N[cc]; }

    if (sch + 1 < NSCH) {              // issue next chunk; hides under cvt+MFMA
      const int soff = (sch + 1) * 32;
      #pragma unroll
      for (int cc = 0; cc < CB; ++cc) {
        aN[cc]  = *(const short8*)(Ap + (size_t)cc * XQ_CSTRIDE + soff);
        w0N[cc] = *(const float4*)(Bp + (size_t)cc * (Pn * Sn) + soff);
        w1N[cc] = *(const float4*)(Bp + (size_t)cc * (Pn * Sn) + soff + 4);
      }
    }

    #pragma unroll
    for (int cc = 0; cc < CB; ++cc) {
      short8 wb;
      wb[0] = (short)f2bf(u0[cc].x); wb[1] = (short)f2bf(u0[cc].y);
      wb[2] = (short)f2bf(u0[cc].z); wb[3] = (short)f2bf(u0[cc].w);
      wb[4] = (short)f2bf(u1[cc].x); wb[5] = (short)f2bf(u1[cc].y);
      wb[6] = (short)f2bf(u1[cc].z); wb[7] = (short)f2bf(u1[cc].w);
      acc[cc] = __builtin_amdgcn_mfma_f32_16x16x32_bf16(a[cc], wb, acc[cc], 0, 0, 0);
    }
  }

  if (p >= Pn) return;
  // D layout: col = lane&15 (=p), row = kg*4 + reg (=b offset)
  #pragma unroll
  for (int r = 0; r < 4; ++r) {
    const int bo = b_base + kg * 4 + r;
    const float4 xl = *(const float4*)&x[(size_t)(bo * Sn + Sn - 1) * Cn + c0];
    float4 st;
    st.x = acc[0][r] + bias[(size_t)(c0 + 0) * Pn + p] + xl.x;
    st.y = acc[1][r] + bias[(size_t)(c0 + 1) * Pn + p] + xl.y;
    st.z = acc[2][r] + bias[(size_t)(c0 + 2) * Pn + p] + xl.z;
    st.w = acc[3][r] + bias[(size_t)(c0 + 3) * Pn + p] + xl.w;
    *(float4*)&out[(size_t)(bo * Pn + p) * Cn + c0] = st;
  }
}

extern "C" void kernel_launch(void* const* d_in, const int* in_sizes, int n_in,
                              void* d_out, int out_size, void* d_ws, size_t ws_size,
                              hipStream_t stream) {
  (void)in_sizes; (void)n_in; (void)out_size; (void)ws_size;  // needs ws >= 86,016,000 B
  const float* x  = (const float*)d_in[0];
  const float* W  = (const float*)d_in[1];
  const float* bv = (const float*)d_in[2];
  float* out = (float*)d_out;
  unsigned short* xq = (unsigned short*)d_ws;

  hipLaunchKernelGGL(xpose_kernel, dim3(Bn, Sn / TS, (Cn + TC - 1) / TC), dim3(256), 0, stream,
                     x, xq);
  hipLaunchKernelGGL(gemm_kernel, dim3(22, Cn / CB), dim3(256), 0, stream,
                     xq, W, bv, x, out);
}

// Round 5
// 257.613 us; speedup vs baseline: 13.1537x; 1.4292x over previous
//
#include <hip/hip_runtime.h>

// out[b,p,c] = sum_s (x[b,s,c]-x[b,S-1,c]) * W[c,p,s] + bias[c,p] + x[b,S-1,c]
//   1) xpose: x'(c,b,s) = bf16(x[b,s,c]-x[b,S-1,c]) into d_ws (86 MB) — BW floor.
//   2) gemm : block = 4 waves, tile 128b x 16p x 4c. W fp32 staged to LDS as bf16
//      (double-buffered, swizzled), read from HBM exactly once. A direct-global,
//      prefetched. mfma_f32_16x16x32_bf16.

typedef __attribute__((ext_vector_type(8))) short short8;   // 8 bf16
typedef __attribute__((ext_vector_type(4))) float floatx4;  // MFMA C/D

namespace {
constexpr int Bn = 128, Sn = 672, Pn = 168, Cn = 500;
constexpr int XQ_CSTRIDE = Bn * Sn;   // bf16 elems per c-plane of x'
constexpr int TC = 64, TS = 96, TROW = TS + 12;   // xpose tile
constexpr int CB = 4;                 // c-planes per block (500 = 4*125)
constexpr int NSCH = Sn / 32;         // 21 chunks of 32 s
constexpr int LDS_CH = CB * 16 * 32;  // 2048 ushort = 4 KB per buffer
}

__device__ __forceinline__ unsigned short f2bf(float f) {  // RTNE f32->bf16
  unsigned int u = __builtin_bit_cast(unsigned int, f);
  u += 0x7fffu + ((u >> 16) & 1u);
  return (unsigned short)(u >> 16);
}

__device__ __forceinline__ short8 pack8(const float4 a, const float4 b) {
  short8 r;
  r[0] = (short)f2bf(a.x); r[1] = (short)f2bf(a.y);
  r[2] = (short)f2bf(a.z); r[3] = (short)f2bf(a.w);
  r[4] = (short)f2bf(b.x); r[5] = (short)f2bf(b.y);
  r[6] = (short)f2bf(b.z); r[7] = (short)f2bf(b.w);
  return r;
}

// ---------------------------------------------------------------- xpose ----
__global__ __launch_bounds__(256)
void xpose_kernel(const float* __restrict__ x, unsigned short* __restrict__ xq) {
  __shared__ unsigned short T[TC][TROW];
  const int b  = blockIdx.x;
  const int s0 = blockIdx.y * TS;
  const int c0 = blockIdx.z * TC;
  const int t  = threadIdx.x;

  #pragma unroll
  for (int i = 0; i < 6; ++i) {
    const int idx = t + i * 256;       // 96 s-rows x 16 c-quads
    const int sr  = idx >> 4;
    const int cq  = (idx & 15) * 4;
    int c = c0 + cq;
    if (c > Cn - 4) c = Cn - 4;        // clamp (16B-aligned); dup writes identical
    const int rel = c - c0;
    const float4 xv = *(const float4*)&x[(size_t)(b * Sn + s0 + sr) * Cn + c];
    const float4 xl = *(const float4*)&x[(size_t)(b * Sn + (Sn - 1)) * Cn + c];
    T[rel + 0][sr] = f2bf(xv.x - xl.x);
    T[rel + 1][sr] = f2bf(xv.y - xl.y);
    T[rel + 2][sr] = f2bf(xv.z - xl.z);
    T[rel + 3][sr] = f2bf(xv.w - xl.w);
  }
  __syncthreads();
  #pragma unroll
  for (int i = 0; i < 6; ++i) {
    const int idx = t + i * 256;       // 64 c-rows x 24 s-quads
    const int cr  = idx / 24;
    const int sq  = (idx % 24) * 4;
    const int c   = c0 + cr;
    if (c >= Cn) continue;
    const ushort4 v = *(const ushort4*)&T[cr][sq];
    *(ushort4*)&xq[(size_t)c * XQ_CSTRIDE + b * Sn + s0 + sq] = v;
  }
}

// ----------------------------------------------------------------- gemm ----
// grid (11 pt, 125 cr), block 256 = 4 waves; wave w: b in [32w, 32w+32).
// Per sch (32 s): stage W chunk (16p x 32s x 4c, fp32->bf16) to LDS dbuf,
// 1 barrier; each wave: 4 ds_read_b128 (B-frags) + 8 A-loads + 8 MFMA.
__global__ __launch_bounds__(256, 4)
void gemm_kernel(const unsigned short* __restrict__ xq, const float* __restrict__ W,
                 const float* __restrict__ bias, const float* __restrict__ x,
                 float* __restrict__ out) {
  __shared__ unsigned short Wl[2][LDS_CH];  // 8 KB total

  const int pt = blockIdx.x;          // 0..10
  const int c0 = blockIdx.y * CB;     // 0..496 exact
  const int tid  = threadIdx.x;
  const int lane = tid & 63;
  const int wave = tid >> 6;
  const int r16  = lane & 15;
  const int kg   = lane >> 4;
  const int p0   = pt * 16;

  // ---- staging role: thread t loads 32B fp32 of row (cc, p) at quad q ----
  const int s_q  = tid & 3;
  const int s_p  = (tid >> 2) & 15;
  const int s_cc = tid >> 6;
  const int sp   = p0 + s_p;
  const int sp_cl = (sp < Pn) ? sp : (Pn - 1);
  const float* Wg = W + ((size_t)(c0 + s_cc) * Pn + sp_cl) * Sn + s_q * 8;
  // LDS granule-XOR swizzle: granule g = q ^ ((p>>1)&3)  (2-way max both phases)
  const int wr_off = (s_cc * 16 + s_p) * 32 + ((s_q ^ ((s_p >> 1) & 3)) * 8);

  // ---- compute role ----
  const int p = p0 + r16;
  const int rd_base = r16 * 32 + ((kg ^ ((r16 >> 1) & 3)) * 8);  // + cc*512
  const unsigned short* Ab =
      xq + (size_t)c0 * XQ_CSTRIDE + (size_t)(wave * 32 + r16) * Sn + kg * 8;

  floatx4 acc[CB][2];
  #pragma unroll
  for (int cc = 0; cc < CB; ++cc) {
    acc[cc][0] = (floatx4){0.f, 0.f, 0.f, 0.f};
    acc[cc][1] = (floatx4){0.f, 0.f, 0.f, 0.f};
  }

  // ---- prologue: W chunk 0 -> LDS buf0; A chunk 0 -> regs ----
  float4 wA = *(const float4*)(Wg);
  float4 wB = *(const float4*)(Wg + 4);
  short8 aN[2][CB];
  #pragma unroll
  for (int sub = 0; sub < 2; ++sub)
    #pragma unroll
    for (int cc = 0; cc < CB; ++cc)
      aN[sub][cc] = *(const short8*)(Ab + (size_t)cc * XQ_CSTRIDE + sub * (16 * Sn));
  *(short8*)&Wl[0][wr_off] = pack8(wA, wB);
  __syncthreads();

  for (int sch = 0; sch < NSCH; ++sch) {
    const int cur = sch & 1;
    short8 a[2][CB];
    #pragma unroll
    for (int sub = 0; sub < 2; ++sub)
      #pragma unroll
      for (int cc = 0; cc < CB; ++cc) a[sub][cc] = aN[sub][cc];

    if (sch + 1 < NSCH) {   // issue next chunk's global loads (hide under MFMA)
      const int soff = (sch + 1) * 32;
      wA = *(const float4*)(Wg + soff);
      wB = *(const float4*)(Wg + soff + 4);
      #pragma unroll
      for (int sub = 0; sub < 2; ++sub)
        #pragma unroll
        for (int cc = 0; cc < CB; ++cc)
          aN[sub][cc] =
              *(const short8*)(Ab + (size_t)cc * XQ_CSTRIDE + sub * (16 * Sn) + soff);
    }

    #pragma unroll
    for (int cc = 0; cc < CB; ++cc) {
      const short8 wb = *(const short8*)&Wl[cur][cc * 512 + rd_base];
      acc[cc][0] = __builtin_amdgcn_mfma_f32_16x16x32_bf16(a[0][cc], wb, acc[cc][0], 0, 0, 0);
      acc[cc][1] = __builtin_amdgcn_mfma_f32_16x16x32_bf16(a[1][cc], wb, acc[cc][1], 0, 0, 0);
    }

    if (sch + 1 < NSCH)     // write next chunk to the other buffer
      *(short8*)&Wl[cur ^ 1][wr_off] = pack8(wA, wB);
    __syncthreads();
  }

  // ---- epilogue: + bias + xlast, store ----
  if (p >= Pn) return;
  float bi[CB];
  #pragma unroll
  for (int cc = 0; cc < CB; ++cc) bi[cc] = bias[(size_t)(c0 + cc) * Pn + p];
  #pragma unroll
  for (int sub = 0; sub < 2; ++sub) {
    #pragma unroll
    for (int r = 0; r < 4; ++r) {
      const int bo = wave * 32 + sub * 16 + kg * 4 + r;
      const float4 xl = *(const float4*)&x[(size_t)(bo * Sn + Sn - 1) * Cn + c0];
      float4 st;
      st.x = acc[0][sub][r] + bi[0] + xl.x;
      st.y = acc[1][sub][r] + bi[1] + xl.y;
      st.z = acc[2][sub][r] + bi[2] + xl.z;
      st.w = acc[3][sub][r] + bi[3] + xl.w;
      *(float4*)&out[(size_t)(bo * Pn + p) * Cn + c0] = st;
    }
  }
}

extern "C" void kernel_launch(void* const* d_in, const int* in_sizes, int n_in,
                              void* d_out, int out_size, void* d_ws, size_t ws_size,
                              hipStream_t stream) {
  (void)in_sizes; (void)n_in; (void)out_size; (void)ws_size;  // needs ws >= 86,016,000 B
  const float* x  = (const float*)d_in[0];
  const float* W  = (const float*)d_in[1];
  const float* bv = (const float*)d_in[2];
  float* out = (float*)d_out;
  unsigned short* xq = (unsigned short*)d_ws;

  hipLaunchKernelGGL(xpose_kernel, dim3(Bn, Sn / TS, (Cn + TC - 1) / TC), dim3(256), 0, stream,
                     x, xq);
  hipLaunchKernelGGL(gemm_kernel, dim3(11, Cn / CB), dim3(256), 0, stream,
                     xq, W, bv, x, out);
}

// Round 6
// 193.716 us; speedup vs baseline: 17.4924x; 1.3298x over previous
//
#include <hip/hip_runtime.h>

// out[b,p,c] = sum_s (x[b,s,c]-x[b,S-1,c]) * W[c,p,s] + bias[c,p] + x[b,S-1,c]
//   1) xpose: x'(c,b,s) = bf16(x[b,s,c]-x[b,S-1,c]) into d_ws (86 MB) — BW floor.
//   2) gemm : block = 8 waves, tile 128b x 96p(pad) x 2c; BOTH operands staged
//      through LDS (dbuf, XOR-swizzled) so each x'/W byte crosses L1 once.
//      x' read 2x total (2 p-tiles), W read exactly once. grid = 500 blocks.

typedef __attribute__((ext_vector_type(8))) short short8;   // 8 bf16
typedef __attribute__((ext_vector_type(4))) float floatx4;  // MFMA C/D

namespace {
constexpr int Bn = 128, Sn = 672, Pn = 168, Cn = 500;
constexpr int XQ_CSTRIDE = Bn * Sn;   // bf16 elems per c-plane of x'
constexpr int TC = 64, TS = 96, TROW = TS + 12;   // xpose tile
constexpr int BC   = 2;               // c-planes per block (500 = 2*250)
constexpr int BPAD = 96;              // padded p-extent (2 tiles cover 168)
constexpr int NSCH = Sn / 32;         // 21 chunks of 32 s
constexpr int A_ELE = BC * Bn * 32;   // 8192 ushort = 16 KB
constexpr int W_ELE = BC * BPAD * 32; // 6144 ushort = 12 KB
}

__device__ __forceinline__ unsigned short f2bf(float f) {  // RTNE f32->bf16
  unsigned int u = __builtin_bit_cast(unsigned int, f);
  u += 0x7fffu + ((u >> 16) & 1u);
  return (unsigned short)(u >> 16);
}

// ---------------------------------------------------------------- xpose ----
__global__ __launch_bounds__(256)
void xpose_kernel(const float* __restrict__ x, unsigned short* __restrict__ xq) {
  __shared__ unsigned short T[TC][TROW];
  const int b  = blockIdx.x;
  const int s0 = blockIdx.y * TS;
  const int c0 = blockIdx.z * TC;
  const int t  = threadIdx.x;

  #pragma unroll
  for (int i = 0; i < 6; ++i) {
    const int idx = t + i * 256;       // 96 s-rows x 16 c-quads
    const int sr  = idx >> 4;
    const int cq  = (idx & 15) * 4;
    int c = c0 + cq;
    if (c > Cn - 4) c = Cn - 4;        // clamp (16B-aligned); dup writes identical
    const int rel = c - c0;
    const float4 xv = *(const float4*)&x[(size_t)(b * Sn + s0 + sr) * Cn + c];
    const float4 xl = *(const float4*)&x[(size_t)(b * Sn + (Sn - 1)) * Cn + c];
    T[rel + 0][sr] = f2bf(xv.x - xl.x);
    T[rel + 1][sr] = f2bf(xv.y - xl.y);
    T[rel + 2][sr] = f2bf(xv.z - xl.z);
    T[rel + 3][sr] = f2bf(xv.w - xl.w);
  }
  __syncthreads();
  #pragma unroll
  for (int i = 0; i < 6; ++i) {
    const int idx = t + i * 256;       // 64 c-rows x 24 s-quads
    const int cr  = idx / 24;
    const int sq  = (idx % 24) * 4;
    const int c   = c0 + cr;
    if (c >= Cn) continue;
    const ushort4 v = *(const ushort4*)&T[cr][sq];
    *(ushort4*)&xq[(size_t)c * XQ_CSTRIDE + b * Sn + s0 + sq] = v;
  }
}

// ----------------------------------------------------------------- gemm ----
// grid 500 1-D: pt = bid&1 (p-tile, adjacent so siblings share x' in LLC),
// cr = bid>>1 (c-pair). block 512 thr = 8 waves: wave (bw = w&3: 32 b,
// pw = w>>2: 48 p). Per sch: stage A 16 KB + W 24 KB fp32 -> LDS (dbuf),
// prefetched one chunk ahead in regs; 12 MFMA/wave; 1 barrier.
__global__ __launch_bounds__(512, 4)
void gemm_kernel(const unsigned short* __restrict__ xq, const float* __restrict__ W,
                 const float* __restrict__ bias, const float* __restrict__ x,
                 float* __restrict__ out) {
  __shared__ unsigned short As[2][A_ELE];  // [cc][b][32s], granule-XOR swizzled
  __shared__ unsigned short Ws[2][W_ELE];  // [cc][prow][32s], same swizzle

  const int bid = blockIdx.x;
  const int pt  = bid & 1;
  const int c0  = (bid >> 1) * BC;        // 0..498 exact
  const int p_base = pt * BPAD;

  const int tid  = threadIdx.x;
  const int lane = tid & 63;
  const int wave = tid >> 6;
  const int r16  = lane & 15;
  const int kg   = lane >> 4;
  const int bw   = wave & 3;              // b-quadrant (32 b)
  const int pw   = wave >> 2;             // p-half (48 p)

  // ---- A staging descriptors: 1024 x 16B, 2 per thread ----
  int ag[2], aw[2];
  #pragma unroll
  for (int r = 0; r < 2; ++r) {
    const int idx = r * 512 + tid;
    const int g  = idx & 3;               // s-octet
    const int b  = (idx >> 2) & 127;
    const int cc = idx >> 9;
    ag[r] = (c0 + cc) * XQ_CSTRIDE + b * Sn + g * 8;
    aw[r] = (cc * Bn + b) * 32 + ((g ^ (b & 3)) * 8);
  }
  // ---- W staging descriptors: 1536 float4, 3 per thread ----
  int wg[3], ww[3];
  #pragma unroll
  for (int r = 0; r < 3; ++r) {
    const int idx  = r * 512 + tid;
    const int q    = idx & 7;             // float4 within 128B row
    const int row  = idx >> 3;            // 0..191
    const int cc   = row / BPAD;
    const int prow = row - cc * BPAD;
    int p = p_base + prow;
    if (p >= Pn) p = Pn - 1;              // clamp; pad rows feed masked output
    wg[r] = ((c0 + cc) * Pn + p) * Sn + q * 4;
    const int g = q >> 1, half = q & 1;
    ww[r] = (cc * BPAD + prow) * 32 + ((g ^ (prow & 3)) * 8) + half * 4;
  }

  // ---- compute-side ds_read offsets ----
  int ard[2][2];  // [cc][fb]
  int wrd[2][3];  // [cc][fp]
  #pragma unroll
  for (int cc = 0; cc < 2; ++cc) {
    #pragma unroll
    for (int fb = 0; fb < 2; ++fb) {
      const int row = bw * 32 + fb * 16 + r16;
      ard[cc][fb] = (cc * Bn + row) * 32 + ((kg ^ (row & 3)) * 8);
    }
    #pragma unroll
    for (int fp = 0; fp < 3; ++fp) {
      const int prow = pw * 48 + fp * 16 + r16;
      wrd[cc][fp] = (cc * BPAD + prow) * 32 + ((kg ^ (prow & 3)) * 8);
    }
  }

  floatx4 acc[2][3][2];  // [fb][fp][cc]
  #pragma unroll
  for (int fb = 0; fb < 2; ++fb)
    #pragma unroll
    for (int fp = 0; fp < 3; ++fp)
      #pragma unroll
      for (int cc = 0; cc < 2; ++cc)
        acc[fb][fp][cc] = (floatx4){0.f, 0.f, 0.f, 0.f};

  // ---- prologue: stage chunk 0 into buf 0 ----
  {
    short8 av0 = *(const short8*)(xq + ag[0]);
    short8 av1 = *(const short8*)(xq + ag[1]);
    float4 wv0 = *(const float4*)(W + wg[0]);
    float4 wv1 = *(const float4*)(W + wg[1]);
    float4 wv2 = *(const float4*)(W + wg[2]);
    *(short8*)&As[0][aw[0]] = av0;
    *(short8*)&As[0][aw[1]] = av1;
    ushort4 u;
    u.x = f2bf(wv0.x); u.y = f2bf(wv0.y); u.z = f2bf(wv0.z); u.w = f2bf(wv0.w);
    *(ushort4*)&Ws[0][ww[0]] = u;
    u.x = f2bf(wv1.x); u.y = f2bf(wv1.y); u.z = f2bf(wv1.z); u.w = f2bf(wv1.w);
    *(ushort4*)&Ws[0][ww[1]] = u;
    u.x = f2bf(wv2.x); u.y = f2bf(wv2.y); u.z = f2bf(wv2.z); u.w = f2bf(wv2.w);
    *(ushort4*)&Ws[0][ww[2]] = u;
  }
  __syncthreads();

  for (int sch = 0; sch < NSCH; ++sch) {
    const int cur = sch & 1;

    // issue next chunk's global loads first (latency hides under ds_read+MFMA)
    short8 aN0, aN1; float4 wN0, wN1, wN2;
    const bool more = (sch + 1 < NSCH);
    if (more) {
      const int so = (sch + 1) * 32;
      aN0 = *(const short8*)(xq + ag[0] + so);
      aN1 = *(const short8*)(xq + ag[1] + so);
      wN0 = *(const float4*)(W + wg[0] + so);
      wN1 = *(const float4*)(W + wg[1] + so);
      wN2 = *(const float4*)(W + wg[2] + so);
    }

    // compute on buf cur
    #pragma unroll
    for (int cc = 0; cc < 2; ++cc) {
      short8 af[2], wf[3];
      #pragma unroll
      for (int fb = 0; fb < 2; ++fb) af[fb] = *(const short8*)&As[cur][ard[cc][fb]];
      #pragma unroll
      for (int fp = 0; fp < 3; ++fp) wf[fp] = *(const short8*)&Ws[cur][wrd[cc][fp]];
      #pragma unroll
      for (int fb = 0; fb < 2; ++fb)
        #pragma unroll
        for (int fp = 0; fp < 3; ++fp)
          acc[fb][fp][cc] =
              __builtin_amdgcn_mfma_f32_16x16x32_bf16(af[fb], wf[fp], acc[fb][fp][cc], 0, 0, 0);
    }

    // write next chunk into the other buffer
    if (more) {
      *(short8*)&As[cur ^ 1][aw[0]] = aN0;
      *(short8*)&As[cur ^ 1][aw[1]] = aN1;
      ushort4 u;
      u.x = f2bf(wN0.x); u.y = f2bf(wN0.y); u.z = f2bf(wN0.z); u.w = f2bf(wN0.w);
      *(ushort4*)&Ws[cur ^ 1][ww[0]] = u;
      u.x = f2bf(wN1.x); u.y = f2bf(wN1.y); u.z = f2bf(wN1.z); u.w = f2bf(wN1.w);
      *(ushort4*)&Ws[cur ^ 1][ww[1]] = u;
      u.x = f2bf(wN2.x); u.y = f2bf(wN2.y); u.z = f2bf(wN2.z); u.w = f2bf(wN2.w);
      *(ushort4*)&Ws[cur ^ 1][ww[2]] = u;
    }
    __syncthreads();
  }

  // ---- epilogue: out = acc + bias + xlast (float2 over the c-pair) ----
  float2 xl[2][4];
  #pragma unroll
  for (int fb = 0; fb < 2; ++fb)
    #pragma unroll
    for (int r = 0; r < 4; ++r) {
      const int b = bw * 32 + fb * 16 + kg * 4 + r;
      xl[fb][r] = *(const float2*)&x[(size_t)(b * Sn + Sn - 1) * Cn + c0];
    }
  #pragma unroll
  for (int fp = 0; fp < 3; ++fp) {
    const int p = p_base + pw * 48 + fp * 16 + r16;   // D col = lane&15 = p
    if (p >= Pn) continue;
    const float b0 = bias[(size_t)(c0 + 0) * Pn + p];
    const float b1 = bias[(size_t)(c0 + 1) * Pn + p];
    #pragma unroll
    for (int fb = 0; fb < 2; ++fb)
      #pragma unroll
      for (int r = 0; r < 4; ++r) {
        const int b = bw * 32 + fb * 16 + kg * 4 + r; // D row = kg*4 + reg
        float2 st;
        st.x = acc[fb][fp][0][r] + b0 + xl[fb][r].x;
        st.y = acc[fb][fp][1][r] + b1 + xl[fb][r].y;
        *(float2*)&out[(size_t)(b * Pn + p) * Cn + c0] = st;
      }
  }
}

extern "C" void kernel_launch(void* const* d_in, const int* in_sizes, int n_in,
                              void* d_out, int out_size, void* d_ws, size_t ws_size,
                              hipStream_t stream) {
  (void)in_sizes; (void)n_in; (void)out_size; (void)ws_size;  // needs ws >= 86,016,000 B
  const float* x  = (const float*)d_in[0];
  const float* W  = (const float*)d_in[1];
  const float* bv = (const float*)d_in[2];
  float* out = (float*)d_out;
  unsigned short* xq = (unsigned short*)d_ws;

  hipLaunchKernelGGL(xpose_kernel, dim3(Bn, Sn / TS, (Cn + TC - 1) / TC), dim3(256), 0, stream,
                     x, xq);
  hipLaunchKernelGGL(gemm_kernel, dim3(500), dim3(512), 0, stream,
                     xq, W, bv, x, out);
}

// Round 7
// 171.423 us; speedup vs baseline: 19.7672x; 1.1300x over previous
//
#include <hip/hip_runtime.h>

// out[b,p,c] = sum_s (x[b,s,c]-x[b,S-1,c]) * W[c,p,s] + bias[c,p] + x[b,S-1,c]
//   1) xpose: x'(c,b,s) = bf16(x[b,s,c]-x[b,S-1,c]) into d_ws (86 MB) — BW floor.
//   2) gemm : block = 8 waves, tile 128b x 96p(pad) x 2c; both operands LDS-staged.
//      R7: XCD-grouped work remap (the 8 c-pair blocks sharing each output line
//      co-run on one XCD -> L2 write-combining), depth-2 register prefetch,
//      (row>>1)&3 bank swizzle.

typedef __attribute__((ext_vector_type(8))) short short8;   // 8 bf16
typedef __attribute__((ext_vector_type(4))) float floatx4;  // MFMA C/D

namespace {
constexpr int Bn = 128, Sn = 672, Pn = 168, Cn = 500;
constexpr int XQ_CSTRIDE = Bn * Sn;   // bf16 elems per c-plane of x'
constexpr int TC = 64, TS = 96, TROW = TS + 12;   // xpose tile
constexpr int BC   = 2;               // c-planes per block (500 = 2*250)
constexpr int BPAD = 96;              // padded p-extent (2 tiles cover 168)
constexpr int NSCH = Sn / 32;         // 21 chunks of 32 s
constexpr int A_ELE = BC * Bn * 32;   // 8192 ushort = 16 KB
constexpr int W_ELE = BC * BPAD * 32; // 6144 ushort = 12 KB
constexpr int NWORK = 500;
}

__device__ __forceinline__ unsigned short f2bf(float f) {  // RTNE f32->bf16
  unsigned int u = __builtin_bit_cast(unsigned int, f);
  u += 0x7fffu + ((u >> 16) & 1u);
  return (unsigned short)(u >> 16);
}

// ---------------------------------------------------------------- xpose ----
__global__ __launch_bounds__(256)
void xpose_kernel(const float* __restrict__ x, unsigned short* __restrict__ xq) {
  __shared__ unsigned short T[TC][TROW];
  const int b  = blockIdx.x;
  const int s0 = blockIdx.y * TS;
  const int c0 = blockIdx.z * TC;
  const int t  = threadIdx.x;

  #pragma unroll
  for (int i = 0; i < 6; ++i) {
    const int idx = t + i * 256;       // 96 s-rows x 16 c-quads
    const int sr  = idx >> 4;
    const int cq  = (idx & 15) * 4;
    int c = c0 + cq;
    if (c > Cn - 4) c = Cn - 4;        // clamp (16B-aligned); dup writes identical
    const int rel = c - c0;
    const float4 xv = *(const float4*)&x[(size_t)(b * Sn + s0 + sr) * Cn + c];
    const float4 xl = *(const float4*)&x[(size_t)(b * Sn + (Sn - 1)) * Cn + c];
    T[rel + 0][sr] = f2bf(xv.x - xl.x);
    T[rel + 1][sr] = f2bf(xv.y - xl.y);
    T[rel + 2][sr] = f2bf(xv.z - xl.z);
    T[rel + 3][sr] = f2bf(xv.w - xl.w);
  }
  __syncthreads();
  #pragma unroll
  for (int i = 0; i < 6; ++i) {
    const int idx = t + i * 256;       // 64 c-rows x 24 s-quads
    const int cr  = idx / 24;
    const int sq  = (idx % 24) * 4;
    const int c   = c0 + cr;
    if (c >= Cn) continue;
    const ushort4 v = *(const ushort4*)&T[cr][sq];
    *(ushort4*)&xq[(size_t)c * XQ_CSTRIDE + b * Sn + s0 + sq] = v;
  }
}

// ----------------------------------------------------------------- gemm ----
// grid 512 (12 dead); wid = (bid&7)*64 + (bid>>3): each XCD owns 64 consecutive
// work-ids = 4 groups of 16 = {8 c-pairs x 2 pt} sharing output lines & x'.
// block 512 thr = 8 waves: wave (bw=w&3: 32 b, pw=w>>2: 48 p). Per sch (32 s):
// stage A 16 KB (bf16) + W 24 KB (fp32->bf16) to LDS dbuf; 12 MFMA/wave;
// depth-2 register prefetch; 1 barrier per sch.
__global__ __launch_bounds__(512, 4)
void gemm_kernel(const unsigned short* __restrict__ xq, const float* __restrict__ W,
                 const float* __restrict__ bias, const float* __restrict__ x,
                 float* __restrict__ out) {
  __shared__ unsigned short As[2][A_ELE];
  __shared__ unsigned short Ws[2][W_ELE];

  const int wid = (blockIdx.x & 7) * 64 + (blockIdx.x >> 3);
  if (wid >= NWORK) return;
  const int pt = wid & 1;
  const int c0 = (wid >> 1) * BC;         // 0..498
  const int p_base = pt * BPAD;

  const int tid  = threadIdx.x;
  const int lane = tid & 63;
  const int wave = tid >> 6;
  const int r16  = lane & 15;
  const int kg   = lane >> 4;
  const int bw   = wave & 3;
  const int pw   = wave >> 2;

  // ---- A staging descriptors: 1024 x 16B, 2 per thread ----
  int ag[2], aw[2];
  #pragma unroll
  for (int r = 0; r < 2; ++r) {
    const int idx = r * 512 + tid;
    const int g  = idx & 3;               // s-octet
    const int b  = (idx >> 2) & 127;
    const int cc = idx >> 9;
    ag[r] = (c0 + cc) * XQ_CSTRIDE + b * Sn + g * 8;
    aw[r] = (cc * Bn + b) * 32 + ((g ^ ((b >> 1) & 3)) * 8);
  }
  // ---- W staging descriptors: 1536 float4, 3 per thread ----
  int wg[3], ww[3];
  #pragma unroll
  for (int r = 0; r < 3; ++r) {
    const int idx  = r * 512 + tid;
    const int q    = idx & 7;             // float4 within 128B row
    const int row  = idx >> 3;            // 0..191
    const int cc   = row / BPAD;
    const int prow = row - cc * BPAD;
    int p = p_base + prow;
    if (p >= Pn) p = Pn - 1;              // clamp; pad rows feed masked output
    wg[r] = ((c0 + cc) * Pn + p) * Sn + q * 4;
    const int g = q >> 1, half = q & 1;
    ww[r] = (cc * BPAD + prow) * 32 + ((g ^ ((prow >> 1) & 3)) * 8) + half * 4;
  }

  // ---- compute-side ds_read offsets ----
  int ard[2][2];  // [cc][fb]
  int wrd[2][3];  // [cc][fp]
  #pragma unroll
  for (int cc = 0; cc < 2; ++cc) {
    #pragma unroll
    for (int fb = 0; fb < 2; ++fb) {
      const int row = bw * 32 + fb * 16 + r16;
      ard[cc][fb] = (cc * Bn + row) * 32 + ((kg ^ ((row >> 1) & 3)) * 8);
    }
    #pragma unroll
    for (int fp = 0; fp < 3; ++fp) {
      const int prow = pw * 48 + fp * 16 + r16;
      wrd[cc][fp] = (cc * BPAD + prow) * 32 + ((kg ^ ((prow >> 1) & 3)) * 8);
    }
  }

  floatx4 acc[2][3][2];  // [fb][fp][cc]
  #pragma unroll
  for (int fb = 0; fb < 2; ++fb)
    #pragma unroll
    for (int fp = 0; fp < 3; ++fp)
      #pragma unroll
      for (int cc = 0; cc < 2; ++cc)
        acc[fb][fp][cc] = (floatx4){0.f, 0.f, 0.f, 0.f};

  // ---- depth-2 prefetch register sets (static names; rule #20) ----
  short8 rA0a, rA0b; float4 rW0a, rW0b, rW0c;   // set R0
  short8 rA1a, rA1b; float4 rW1a, rW1b, rW1c;   // set R1

  auto load0 = [&](int sch) {
    const int so = sch * 32;
    rA0a = *(const short8*)(xq + ag[0] + so);
    rA0b = *(const short8*)(xq + ag[1] + so);
    rW0a = *(const float4*)(W + wg[0] + so);
    rW0b = *(const float4*)(W + wg[1] + so);
    rW0c = *(const float4*)(W + wg[2] + so);
  };
  auto load1 = [&](int sch) {
    const int so = sch * 32;
    rA1a = *(const short8*)(xq + ag[0] + so);
    rA1b = *(const short8*)(xq + ag[1] + so);
    rW1a = *(const float4*)(W + wg[0] + so);
    rW1b = *(const float4*)(W + wg[1] + so);
    rW1c = *(const float4*)(W + wg[2] + so);
  };
  auto store0 = [&](int buf) {
    *(short8*)&As[buf][aw[0]] = rA0a;
    *(short8*)&As[buf][aw[1]] = rA0b;
    ushort4 u;
    u.x = f2bf(rW0a.x); u.y = f2bf(rW0a.y); u.z = f2bf(rW0a.z); u.w = f2bf(rW0a.w);
    *(ushort4*)&Ws[buf][ww[0]] = u;
    u.x = f2bf(rW0b.x); u.y = f2bf(rW0b.y); u.z = f2bf(rW0b.z); u.w = f2bf(rW0b.w);
    *(ushort4*)&Ws[buf][ww[1]] = u;
    u.x = f2bf(rW0c.x); u.y = f2bf(rW0c.y); u.z = f2bf(rW0c.z); u.w = f2bf(rW0c.w);
    *(ushort4*)&Ws[buf][ww[2]] = u;
  };
  auto store1 = [&](int buf) {
    *(short8*)&As[buf][aw[0]] = rA1a;
    *(short8*)&As[buf][aw[1]] = rA1b;
    ushort4 u;
    u.x = f2bf(rW1a.x); u.y = f2bf(rW1a.y); u.z = f2bf(rW1a.z); u.w = f2bf(rW1a.w);
    *(ushort4*)&Ws[buf][ww[0]] = u;
    u.x = f2bf(rW1b.x); u.y = f2bf(rW1b.y); u.z = f2bf(rW1b.z); u.w = f2bf(rW1b.w);
    *(ushort4*)&Ws[buf][ww[1]] = u;
    u.x = f2bf(rW1c.x); u.y = f2bf(rW1c.y); u.z = f2bf(rW1c.z); u.w = f2bf(rW1c.w);
    *(ushort4*)&Ws[buf][ww[2]] = u;
  };
  auto compute = [&](int buf) {
    #pragma unroll
    for (int cc = 0; cc < 2; ++cc) {
      short8 af[2], wf[3];
      #pragma unroll
      for (int fb = 0; fb < 2; ++fb) af[fb] = *(const short8*)&As[buf][ard[cc][fb]];
      #pragma unroll
      for (int fp = 0; fp < 3; ++fp) wf[fp] = *(const short8*)&Ws[buf][wrd[cc][fp]];
      #pragma unroll
      for (int fb = 0; fb < 2; ++fb)
        #pragma unroll
        for (int fp = 0; fp < 3; ++fp)
          acc[fb][fp][cc] =
              __builtin_amdgcn_mfma_f32_16x16x32_bf16(af[fb], wf[fp], acc[fb][fp][cc], 0, 0, 0);
    }
  };

  // ---- prologue ----
  load0(0);                 // R0 <- chunk 0
  load1(1);                 // R1 <- chunk 1 (stays in flight across store0)
  store0(0);                // LDS0 <- chunk 0
  __syncthreads();

  // ---- main loop: NSCH = 21 chunks, unrolled x2 with static buffer roles ----
  #pragma unroll 1
  for (int k = 0; k < NSCH - 1; k += 2) {
    if (k + 2 < NSCH) load0(k + 2);   // in flight through 2 compute phases
    compute(0);                        // chunk k
    store1(1);                         // LDS1 <- chunk k+1 (loads long landed)
    __syncthreads();
    if (k + 3 < NSCH) load1(k + 3);
    compute(1);                        // chunk k+1
    if (k + 2 < NSCH) store0(0);       // LDS0 <- chunk k+2
    __syncthreads();
  }
  compute(0);                          // chunk 20 (NSCH odd)

  // ---- epilogue: out = acc + bias + xlast (float2 over the c-pair) ----
  float2 xl[2][4];
  #pragma unroll
  for (int fb = 0; fb < 2; ++fb)
    #pragma unroll
    for (int r = 0; r < 4; ++r) {
      const int b = bw * 32 + fb * 16 + kg * 4 + r;
      xl[fb][r] = *(const float2*)&x[(size_t)(b * Sn + Sn - 1) * Cn + c0];
    }
  #pragma unroll
  for (int fp = 0; fp < 3; ++fp) {
    const int p = p_base + pw * 48 + fp * 16 + r16;   // D col = lane&15 = p
    if (p >= Pn) continue;
    const float b0 = bias[(size_t)(c0 + 0) * Pn + p];
    const float b1 = bias[(size_t)(c0 + 1) * Pn + p];
    #pragma unroll
    for (int fb = 0; fb < 2; ++fb)
      #pragma unroll
      for (int r = 0; r < 4; ++r) {
        const int b = bw * 32 + fb * 16 + kg * 4 + r; // D row = kg*4 + reg
        float2 st;
        st.x = acc[fb][fp][0][r] + b0 + xl[fb][r].x;
        st.y = acc[fb][fp][1][r] + b1 + xl[fb][r].y;
        *(float2*)&out[(size_t)(b * Pn + p) * Cn + c0] = st;
      }
  }
}

extern "C" void kernel_launch(void* const* d_in, const int* in_sizes, int n_in,
                              void* d_out, int out_size, void* d_ws, size_t ws_size,
                              hipStream_t stream) {
  (void)in_sizes; (void)n_in; (void)out_size; (void)ws_size;  // needs ws >= 86,016,000 B
  const float* x  = (const float*)d_in[0];
  const float* W  = (const float*)d_in[1];
  const float* bv = (const float*)d_in[2];
  float* out = (float*)d_out;
  unsigned short* xq = (unsigned short*)d_ws;

  hipLaunchKernelGGL(xpose_kernel, dim3(Bn, Sn / TS, (Cn + TC - 1) / TC), dim3(256), 0, stream,
                     x, xq);
  hipLaunchKernelGGL(gemm_kernel, dim3(512), dim3(512), 0, stream,
                     xq, W, bv, x, out);
}